// Round 4
// baseline (333.027 us; speedup 1.0000x reference)
//
#include <hip/hip_runtime.h>

// Problem constants
#define Bb 256
#define Kk 256
#define NCLS 10

typedef __attribute__((ext_vector_type(8))) short short8;
typedef __attribute__((ext_vector_type(4))) float f32x4;

__device__ __forceinline__ float bf2f(ushort u) {
    return __uint_as_float(((unsigned int)u) << 16);
}
__device__ __forceinline__ ushort f2bf(float f) {
    unsigned int u = __float_as_uint(f);
    u = (u + 0x7FFFu + ((u >> 16) & 1u)) >> 16;
    return (ushort)u;
}
// fast tanh: (e^2v - 1)/(e^2v + 1)
__device__ __forceinline__ float tanh_fast(float v) {
    float t = __expf(2.f * v);
    return (t - 1.f) / (t + 1.f);
}

// ---------------------------------------------------------------------------
// Per-(pair i, side a, j-half jt) GEMM: proj[b, i, a, j] =
//   sum_k h_l[b, 2i+a, k] * softmax(W[i,a,:,:], axis=k)[k, j]
// softmax fused as (h @ exp(W)) * 1/colsum(exp(W)).
// h_l rows are formed on the fly:
//   FIRST:  h_0[b,d,k] = tanh(x[b,d] * W_in[d,k])          (rank-1)
//   else :  h_l[b,d,k] = proj_prev[b,d,0,k]*proj_prev[b,d,1,k]
// Tiling: BM=256 (all of B), BN=128 (j-half), BK=32.
// 4 waves (2 wm x 2 wn), wave tile 128x64 -> 8x4 mfma_f32_16x16x32_bf16 frags.
// ---------------------------------------------------------------------------
template<bool FIRST>
__global__ __launch_bounds__(256, 2)
void level_kernel(const float*  __restrict__ x,          // (B, D)      [FIRST]
                  const float*  __restrict__ Win,        // (D, K)      [FIRST]
                  const ushort* __restrict__ proj_prev,  // (B, 2n, 2, K) bf16
                  const float*  __restrict__ W,          // (n, 2, K, K) fp32
                  ushort*       __restrict__ proj_out,   // (B, n, 2, K) bf16
                  int n)
{
    __shared__ __align__(16) ushort sA[256 * 40];   // A tile, rows 80B (32 k + pad)
    __shared__ __align__(16) ushort sE[128 * 40];   // exp(W) tile, [j][k], 80B rows
    __shared__ float sRed[2][128];
    __shared__ float sRcp[128];

    const int tid = threadIdx.x;
    const int a   = blockIdx.x >> 1;
    const int jt  = blockIdx.x & 1;
    const int i   = blockIdx.y;
    const int d   = 2 * i + a;

    const int l   = tid & 63;
    const int l15 = l & 15;
    const int g   = l >> 4;          // k-slot group 0..3
    const int w   = tid >> 6;
    const int wm  = w >> 1;          // 0..1 : row half
    const int wn  = w & 1;           // 0..1 : col half

    // E staging ids
    const int ej  = tid & 127;       // j within 128-col half
    const int ekq = tid >> 7;        // 0..1 : k 16-half

    f32x4 acc[8][4];
    #pragma unroll
    for (int mf = 0; mf < 8; ++mf)
        #pragma unroll
        for (int nf = 0; nf < 4; ++nf)
            acc[mf][nf] = (f32x4){0.f, 0.f, 0.f, 0.f};

    float csum = 0.f;

    const size_t wbase = ((size_t)(i * 2 + a)) * (size_t)(Kk * Kk);

    for (int k0 = 0; k0 < Kk; k0 += 32) {
        // ---- stage A: 256 rows x 32 k (bf16), rows padded to 40 ushorts ----
        #pragma unroll
        for (int p = 0; p < 4; ++p) {
            const int unit = p * 256 + tid;
            const int m = unit >> 2;        // 0..255 (= b)
            const int s = unit & 3;         // 16B slice
            ushort pk[8];
            if (FIRST) {
                const float4 w0 = *(const float4*)&Win[(size_t)d * Kk + k0 + s * 8];
                const float4 w1 = *(const float4*)&Win[(size_t)d * Kk + k0 + s * 8 + 4];
                const float xv = x[(size_t)m * 256 + d];
                pk[0] = f2bf(tanh_fast(xv * w0.x));
                pk[1] = f2bf(tanh_fast(xv * w0.y));
                pk[2] = f2bf(tanh_fast(xv * w0.z));
                pk[3] = f2bf(tanh_fast(xv * w0.w));
                pk[4] = f2bf(tanh_fast(xv * w1.x));
                pk[5] = f2bf(tanh_fast(xv * w1.y));
                pk[6] = f2bf(tanh_fast(xv * w1.z));
                pk[7] = f2bf(tanh_fast(xv * w1.w));
            } else {
                const size_t base = (((size_t)m * (2 * n) + d) * 2) * 256 + k0 + s * 8;
                const short8 p0 = *(const short8*)&proj_prev[base];
                const short8 p1 = *(const short8*)&proj_prev[base + 256];
                #pragma unroll
                for (int e = 0; e < 8; ++e)
                    pk[e] = f2bf(bf2f((ushort)p0[e]) * bf2f((ushort)p1[e]));
            }
            short8 v;
            #pragma unroll
            for (int e = 0; e < 8; ++e) v[e] = (short)pk[e];
            *(short8*)&sA[m * 40 + s * 8] = v;
        }

        // ---- stage E = exp(W) transposed to [j][k]; accumulate colsum ----
        #pragma unroll
        for (int h2 = 0; h2 < 2; ++h2) {
            const int kk = ekq * 16 + h2 * 8;
            ushort pk[8];
            #pragma unroll
            for (int r = 0; r < 8; ++r) {
                const float wv = W[wbase + (size_t)(k0 + kk + r) * 256 + jt * 128 + ej];
                const float e = __expf(wv);
                csum += e;
                pk[r] = f2bf(e);
            }
            short8 v;
            #pragma unroll
            for (int e = 0; e < 8; ++e) v[e] = (short)pk[e];
            *(short8*)&sE[ej * 40 + kk] = v;
        }
        __syncthreads();

        // ---- MFMA: wave tile 128x64 = 8 m-frags x 4 n-frags ----
        short8 bfr[4];
        #pragma unroll
        for (int nf = 0; nf < 4; ++nf)
            bfr[nf] = *(const short8*)&sE[(wn * 64 + nf * 16 + l15) * 40 + g * 8];
        #pragma unroll
        for (int mf = 0; mf < 8; ++mf) {
            const short8 afr = *(const short8*)&sA[(wm * 128 + mf * 16 + l15) * 40 + g * 8];
            #pragma unroll
            for (int nf = 0; nf < 4; ++nf)
                acc[mf][nf] = __builtin_amdgcn_mfma_f32_16x16x32_bf16(
                    afr, bfr[nf], acc[mf][nf], 0, 0, 0);
        }
        __syncthreads();
    }

    // ---- softmax denominators ----
    sRed[ekq][ej] = csum;
    __syncthreads();
    if (tid < 128) sRcp[tid] = 1.f / (sRed[0][tid] + sRed[1][tid]);
    __syncthreads();

    // ---- epilogue: scale by 1/colsum, write bf16 proj ----
    float rj[4];
    #pragma unroll
    for (int nf = 0; nf < 4; ++nf) rj[nf] = sRcp[wn * 64 + nf * 16 + l15];

    #pragma unroll
    for (int mf = 0; mf < 8; ++mf)
        #pragma unroll
        for (int nf = 0; nf < 4; ++nf) {
            const int jloc = wn * 64 + nf * 16 + l15;
            #pragma unroll
            for (int r = 0; r < 4; ++r) {
                const int b = wm * 128 + mf * 16 + g * 4 + r;
                const size_t off = (((size_t)b * n + i) * 2 + a) * 256 + jt * 128 + jloc;
                proj_out[off] = f2bf(acc[mf][nf][r] * rj[nf]);
            }
        }
}

// ---------------------------------------------------------------------------
// Head: root[b,k] = proj7[b,0,0,k]*proj7[b,0,1,k];
// out[b,c] = sum_k root[b,k]*exp(Wout[k,c]) / colsum_c
// ---------------------------------------------------------------------------
__global__ __launch_bounds__(256)
void out_kernel(const ushort* __restrict__ proj7,  // (B,1,2,K) bf16
                const float*  __restrict__ Wout,   // (K, NCLS)
                float*        __restrict__ out)    // (B,1,NCLS)
{
    __shared__ float sR[16][260];
    __shared__ float sE[256][12];
    __shared__ float sDen[16];

    const int tid = threadIdx.x;
    if (tid < 16) sDen[tid] = 0.f;
    __syncthreads();

    float e[NCLS];
    #pragma unroll
    for (int c = 0; c < NCLS; ++c) {
        e[c] = __expf(Wout[(size_t)tid * NCLS + c]);
        sE[tid][c] = e[c];
    }
    #pragma unroll
    for (int c = 0; c < NCLS; ++c) {
        float v = e[c];
        for (int off = 32; off > 0; off >>= 1) v += __shfl_down(v, off);
        if ((tid & 63) == 0) atomicAdd(&sDen[c], v);
    }

    const int b0 = blockIdx.x * 16;
    #pragma unroll
    for (int v = 0; v < 4; ++v) {
        const int u = v * 256 + tid;
        const int row = u >> 6;
        const int c4 = (u & 63) * 4;
        const size_t base = (size_t)(b0 + row) * 512 + c4;
        const ushort4 p0 = *(const ushort4*)&proj7[base];
        const ushort4 p1 = *(const ushort4*)&proj7[base + 256];
        sR[row][c4 + 0] = bf2f(p0.x) * bf2f(p1.x);
        sR[row][c4 + 1] = bf2f(p0.y) * bf2f(p1.y);
        sR[row][c4 + 2] = bf2f(p0.z) * bf2f(p1.z);
        sR[row][c4 + 3] = bf2f(p0.w) * bf2f(p1.w);
    }
    __syncthreads();

    const int ty = tid >> 4, tx = tid & 15;
    if (tx < NCLS) {
        float s = 0.f;
        for (int k = 0; k < Kk; ++k) s += sR[ty][k] * sE[k][tx];
        out[(size_t)(b0 + ty) * NCLS + tx] = s / sDen[tx];
    }
}

extern "C" void kernel_launch(void* const* d_in, const int* in_sizes, int n_in,
                              void* d_out, int out_size, void* d_ws, size_t ws_size,
                              hipStream_t stream)
{
    const float* x    = (const float*)d_in[0];
    const float* Win  = (const float*)d_in[1];
    const float* Wl[8];
    for (int lv = 0; lv < 8; ++lv) Wl[lv] = (const float*)d_in[2 + lv];
    const float* Wout = (const float*)d_in[10];
    float* out = (float*)d_out;

    // proj ping-pong in workspace (bf16):
    // P0: level-0 proj (256,128,2,256) = 16,777,216 ushorts (32 MiB)
    // P1: level-1 proj (256, 64,2,256) =  8,388,608 ushorts (16 MiB)
    ushort* P0 = (ushort*)d_ws;
    ushort* P1 = P0 + 16777216;

    // level 0: A = tanh(x*Win) generated inline
    level_kernel<true><<<dim3(4, 128), 256, 0, stream>>>(x, Win, nullptr, Wl[0], P0, 128);

    const ushort* cur = P0;
    for (int lv = 1; lv < 8; ++lv) {
        const int n = 128 >> lv;
        ushort* dst = (lv & 1) ? P1 : P0;
        level_kernel<false><<<dim3(4, n), 256, 0, stream>>>(nullptr, nullptr, cur, Wl[lv], dst, n);
        cur = dst;
    }

    // head (level-7 proj is in P1)
    out_kernel<<<dim3(16), 256, 0, stream>>>(cur, Wout, out);
}